// Round 1
// baseline (679.773 us; speedup 1.0000x reference)
//
#include <hip/hip_runtime.h>
#include <hip/hip_bf16.h>
#include <math.h>

// Problem constants: B=4, S=2048, D=256, H=4, HD=64, keep top-10% per row.
// thr = v205 + 0.3*(v204 - v205)  (v_k = (k+1)-th largest, 0-indexed desc sort)

#define CAP 320     // sparse-list capacity per row (kept ~205; ties margin)
#define CAPP 328    // padded capacity (multiple-of-8 batches)

// ---------- helpers ----------
__device__ __forceinline__ unsigned mtu(float f){          // order-preserving float->uint
  unsigned u = __float_as_uint(f);
  return (u & 0x80000000u) ? ~u : (u | 0x80000000u);
}
__device__ __forceinline__ float umt(unsigned u){          // inverse
  return __uint_as_float((u & 0x80000000u) ? (u & 0x7fffffffu) : ~u);
}
__device__ __forceinline__ int wsum_i(int v){
  #pragma unroll
  for (int m=1;m<64;m<<=1) v += __shfl_xor(v,m,64);
  return v;
}
__device__ __forceinline__ float wsum_f(float v){
  #pragma unroll
  for (int m=1;m<64;m<<=1) v += __shfl_xor(v,m,64);
  return v;
}
__device__ __forceinline__ unsigned wmax_u(unsigned v){
  #pragma unroll
  for (int m=1;m<64;m<<=1){ unsigned o=(unsigned)__shfl_xor((int)v,m,64); v = o>v?o:v; }
  return v;
}
__device__ __forceinline__ unsigned wmin_u(unsigned v){
  #pragma unroll
  for (int m=1;m<64;m<<=1){ unsigned o=(unsigned)__shfl_xor((int)v,m,64); v = o<v?o:v; }
  return v;
}

// ---------- K0a: per-(b,chunk) column sums of x ----------
__global__ void xpart_kernel(const float* __restrict__ x, float* __restrict__ xpart){
  const int ch = blockIdx.x, b = blockIdx.y, t = threadIdx.x;
  const float* xp = x + ((size_t)b*2048 + (size_t)ch*128)*256 + t;
  float s = 0.f;
  for (int i=0;i<128;i++) s += xp[(size_t)i*256];
  xpart[(size_t)(b*16+ch)*256 + t] = s;
}

// ---------- K0b: gate[b][256] ----------
__global__ void gate_kernel(const float* __restrict__ xpart,
                            const float* __restrict__ Wg, const float* __restrict__ bg,
                            const float* __restrict__ Wgp,const float* __restrict__ bgp,
                            float* __restrict__ gate_ws){
  __shared__ float xm[256];
  __shared__ float g16[16];
  const int t = threadIdx.x;
  for (int b=0;b<4;b++){
    float s = 0.f;
    for (int ch=0; ch<16; ch++) s += xpart[(size_t)(b*16+ch)*256 + t];
    xm[t] = s * (1.0f/2048.0f);
    __syncthreads();
    if (t < 16){
      float z = bg[t];
      for (int d=0; d<256; d++) z = fmaf(xm[d], Wg[t*256+d], z);
      g16[t] = 1.0f/(1.0f + __expf(-z));
    }
    __syncthreads();
    float z2 = bgp[t];
    #pragma unroll
    for (int j=0;j<16;j++) z2 = fmaf(g16[j], Wgp[t*16+j], z2);
    gate_ws[b*256 + t] = z2;
    __syncthreads();
  }
}

// ---------- K1: fused QKV projection (fp32, 64x64 tile) ----------
__global__ __launch_bounds__(256) void qkv_gemm(
    const float* __restrict__ x,
    const float* __restrict__ Wq, const float* __restrict__ bq,
    const float* __restrict__ Wk, const float* __restrict__ bk,
    const float* __restrict__ Wv, const float* __restrict__ bv,
    float* __restrict__ q_ws, float* __restrict__ kt_ws, float* __restrict__ v_ws){
  __shared__ float As[16][68];
  __shared__ float Bs[16][68];
  const int m0 = blockIdx.x * 64;
  const int n0g = blockIdx.y * 64;          // global col tile in [0,768)
  const int sect = n0g >> 8;                // 0:Q 1:K 2:V
  const int nloc0 = n0g & 255;
  const float* W    = (sect==0) ? Wq : ((sect==1) ? Wk : Wv);
  const float* bias = (sect==0) ? bq : ((sect==1) ? bk : bv);
  const int tid = threadIdx.x;
  const int ty = tid >> 4, tx = tid & 15;
  const int lr = tid >> 2, lc = tid & 3;

  float c[4][4];
  #pragma unroll
  for (int i=0;i<4;i++){
    #pragma unroll
    for (int j=0;j<4;j++) c[i][j]=0.f;
  }

  for (int k0=0; k0<256; k0+=16){
    float4 av  = *(const float4*)&x[(size_t)(m0+lr)*256 + k0 + lc*4];
    float4 bv4 = *(const float4*)&W[(size_t)(nloc0+lr)*256 + k0 + lc*4];
    __syncthreads();
    As[lc*4+0][lr]=av.x;  As[lc*4+1][lr]=av.y;  As[lc*4+2][lr]=av.z;  As[lc*4+3][lr]=av.w;
    Bs[lc*4+0][lr]=bv4.x; Bs[lc*4+1][lr]=bv4.y; Bs[lc*4+2][lr]=bv4.z; Bs[lc*4+3][lr]=bv4.w;
    __syncthreads();
    #pragma unroll
    for (int kk=0; kk<16; kk++){
      float4 a  = *(const float4*)&As[kk][ty*4];
      float4 b4 = *(const float4*)&Bs[kk][tx*4];
      c[0][0]=fmaf(a.x,b4.x,c[0][0]); c[0][1]=fmaf(a.x,b4.y,c[0][1]); c[0][2]=fmaf(a.x,b4.z,c[0][2]); c[0][3]=fmaf(a.x,b4.w,c[0][3]);
      c[1][0]=fmaf(a.y,b4.x,c[1][0]); c[1][1]=fmaf(a.y,b4.y,c[1][1]); c[1][2]=fmaf(a.y,b4.z,c[1][2]); c[1][3]=fmaf(a.y,b4.w,c[1][3]);
      c[2][0]=fmaf(a.z,b4.x,c[2][0]); c[2][1]=fmaf(a.z,b4.y,c[2][1]); c[2][2]=fmaf(a.z,b4.z,c[2][2]); c[2][3]=fmaf(a.z,b4.w,c[2][3]);
      c[3][0]=fmaf(a.w,b4.x,c[3][0]); c[3][1]=fmaf(a.w,b4.y,c[3][1]); c[3][2]=fmaf(a.w,b4.z,c[3][2]); c[3][3]=fmaf(a.w,b4.w,c[3][3]);
    }
  }

  #pragma unroll
  for (int i=0;i<4;i++){
    const int m = m0 + ty*4 + i;
    const int bidx = m >> 11, s = m & 2047;
    #pragma unroll
    for (int j=0;j<4;j++){
      const int f = nloc0 + tx*4 + j;        // feature in [0,256)
      const float val = c[i][j] + bias[f];
      const int hh = f >> 6, hd = f & 63;
      if (sect == 1)
        kt_ws[(size_t)((bidx*4+hh)*64 + hd)*2048 + s] = val;   // K^T: [bh][hd][s]
      else {
        float* dst = (sect==0) ? q_ws : v_ws;                  // [bh][s][hd]
        dst[(size_t)((bidx*4+hh)*2048 + s)*64 + hd] = val;
      }
    }
  }
}

// ---------- K2: sparse attention, one block per (bh, 16-query tile) ----------
__global__ __launch_bounds__(512, 2) void attn_kernel(
    const float* __restrict__ q_ws, const float* __restrict__ kt_ws,
    const float* __restrict__ v_ws, float* __restrict__ att_ws){
  __shared__ float qt[16][64];                       // 4 KB
  __shared__ float buf[16][256];                     // 16 KB handoff chunk
  __shared__ unsigned long long lists[16][CAPP];     // 41 KB sparse (k,p) lists

  const int bh = blockIdx.y;
  const int q0 = blockIdx.x * 16;
  const int tid = threadIdx.x;

  if (tid < 256){
    const int r = tid >> 4, d4 = (tid & 15) * 4;
    *(float4*)&qt[r][d4] = *(const float4*)&q_ws[(size_t)(bh*2048 + q0 + r)*64 + d4];
  }
  __syncthreads();

  // ----- phase 1: scores. thread = (row-group rg of 8 rows) x (8 keys kt*8..) -----
  const int rg = tid >> 8;
  const int kt = tid & 255;
  const float* Kb = kt_ws + (size_t)bh * 64 * 2048;

  float acc[8][8];
  #pragma unroll
  for (int r=0;r<8;r++){
    #pragma unroll
    for (int j=0;j<8;j++) acc[r][j]=0.f;
  }

  for (int d0=0; d0<64; d0+=4){
    float4 qv[8];
    #pragma unroll
    for (int r=0;r<8;r++) qv[r] = *(const float4*)&qt[rg*8+r][d0];
    #pragma unroll
    for (int dd=0; dd<4; dd++){
      const float* kr = &Kb[(size_t)(d0+dd)*2048 + kt*8];
      const float4 ka = *(const float4*)kr;
      const float4 kb = *(const float4*)(kr+4);
      #pragma unroll
      for (int r=0;r<8;r++){
        const float qd = dd==0?qv[r].x : dd==1?qv[r].y : dd==2?qv[r].z : qv[r].w;
        acc[r][0]=fmaf(qd,ka.x,acc[r][0]); acc[r][1]=fmaf(qd,ka.y,acc[r][1]);
        acc[r][2]=fmaf(qd,ka.z,acc[r][2]); acc[r][3]=fmaf(qd,ka.w,acc[r][3]);
        acc[r][4]=fmaf(qd,kb.x,acc[r][4]); acc[r][5]=fmaf(qd,kb.y,acc[r][5]);
        acc[r][6]=fmaf(qd,kb.z,acc[r][6]); acc[r][7]=fmaf(qd,kb.w,acc[r][7]);
      }
    }
  }
  #pragma unroll
  for (int r=0;r<8;r++){
    #pragma unroll
    for (int j=0;j<8;j++) acc[r][j] *= 0.125f;   // scale = HD^-0.5 = 1/8 (exact)
  }

  // ----- phase 2: chunked handoff -> each wave owns 2 full rows in registers -----
  const int w  = tid >> 6;
  const int ln = tid & 63;
  const int myc  = kt >> 5;
  const int kloc = (kt & 31) * 8;
  const int qa = w*2, qb = w*2+1;
  unsigned su0[32], su1[32];

  #pragma unroll
  for (int c=0;c<8;c++){
    __syncthreads();
    if (myc == c){
      #pragma unroll
      for (int r=0;r<8;r++){
        const int row = rg*8 + r;
        *(float4*)&buf[row][kloc]   = make_float4(acc[r][0],acc[r][1],acc[r][2],acc[r][3]);
        *(float4*)&buf[row][kloc+4] = make_float4(acc[r][4],acc[r][5],acc[r][6],acc[r][7]);
      }
    }
    __syncthreads();
    const float4 va = *(const float4*)&buf[qa][ln*4];
    const float4 vb = *(const float4*)&buf[qb][ln*4];
    su0[c*4+0]=mtu(va.x); su0[c*4+1]=mtu(va.y); su0[c*4+2]=mtu(va.z); su0[c*4+3]=mtu(va.w);
    su1[c*4+0]=mtu(vb.x); su1[c*4+1]=mtu(vb.y); su1[c*4+2]=mtu(vb.z); su1[c*4+3]=mtu(vb.w);
  }
  // key index of su[i]: k = (i>>2)*256 + ln*4 + (i&3)

  // ----- phase 3: exact radix binary search for v205 (206th largest) per row -----
  unsigned v0=0, v1=0;
  #pragma unroll 1
  for (int bit=31; bit>=0; --bit){
    const unsigned c0 = v0 | (1u<<bit);
    const unsigned c1 = v1 | (1u<<bit);
    int n0=0, n1=0;
    #pragma unroll
    for (int i=0;i<32;i++){
      n0 += (su0[i] >= c0) ? 1 : 0;
      n1 += (su1[i] >= c1) ? 1 : 0;
    }
    int packed = n0 | (n1<<16);
    packed = wsum_i(packed);
    if ((packed & 0xffff) >= 206) v0 = c0;
    if ((packed >> 16)    >= 206) v1 = c1;
  }

  // ----- phase 4: per-row threshold, softmax, compaction, sparse PV -----
  const int b = bh >> 2, h = bh & 3;
  const float* Vb = v_ws + (size_t)bh * 2048 * 64;
  const unsigned long long lmask = (1ull << ln) - 1ull;

  #pragma unroll
  for (int rr=0; rr<2; rr++){
    const int q = w*2 + rr;
    const unsigned v = rr ? v1 : v0;
    unsigned mx = 0, mn = 0xffffffffu;
    int cgt = 0;
    #pragma unroll
    for (int i=0;i<32;i++){
      const unsigned u = rr ? su1[i] : su0[i];
      mx = (u > mx) ? u : mx;
      const bool gt = (u > v);
      cgt += gt ? 1 : 0;
      mn = (gt && u < mn) ? u : mn;
    }
    mx = wmax_u(mx);
    mn = wmin_u(mn);
    cgt = wsum_i(cgt);
    const unsigned v204 = (cgt == 205) ? mn : v;   // 205th largest
    const float a = umt(v), bb = umt(v204);
    const float thr = (float)((double)a + 0.3*((double)bb - (double)a));
    const float mxf = umt(mx);

    int n = 0; float zl = 0.f;
    #pragma unroll
    for (int i=0;i<32;i++){
      const float s = umt(rr ? su1[i] : su0[i]);
      const bool keep = (s >= thr);
      const unsigned long long bal = __ballot(keep);
      if (keep){
        const float p = __expf(s - mxf);
        zl += p;
        const int pos = n + (int)__popcll(bal & lmask);
        const int k = ((i>>2)<<8) + (ln<<2) + (i&3);
        if (pos < CAP)
          lists[q][pos] = (unsigned long long)(unsigned)k |
                          ((unsigned long long)__float_as_uint(p) << 32);
      }
      n += (int)__popcll(bal);
    }
    float Z = wsum_f(zl);
    if (n > CAP) n = CAP;
    const int npad = (n + 7) & ~7;
    if (ln < npad - n) lists[q][n + ln] = 0ull;     // zero-pad (p=0,k=0)

    float av = 0.f;
    for (int t=0; t<npad; t+=8){
      const unsigned long long e0=lists[q][t+0], e1=lists[q][t+1];
      const unsigned long long e2=lists[q][t+2], e3=lists[q][t+3];
      const unsigned long long e4=lists[q][t+4], e5=lists[q][t+5];
      const unsigned long long e6=lists[q][t+6], e7=lists[q][t+7];
      av = fmaf(__uint_as_float((unsigned)(e0>>32)), Vb[(size_t)((unsigned)e0)*64 + ln], av);
      av = fmaf(__uint_as_float((unsigned)(e1>>32)), Vb[(size_t)((unsigned)e1)*64 + ln], av);
      av = fmaf(__uint_as_float((unsigned)(e2>>32)), Vb[(size_t)((unsigned)e2)*64 + ln], av);
      av = fmaf(__uint_as_float((unsigned)(e3>>32)), Vb[(size_t)((unsigned)e3)*64 + ln], av);
      av = fmaf(__uint_as_float((unsigned)(e4>>32)), Vb[(size_t)((unsigned)e4)*64 + ln], av);
      av = fmaf(__uint_as_float((unsigned)(e5>>32)), Vb[(size_t)((unsigned)e5)*64 + ln], av);
      av = fmaf(__uint_as_float((unsigned)(e6>>32)), Vb[(size_t)((unsigned)e6)*64 + ln], av);
      av = fmaf(__uint_as_float((unsigned)(e7>>32)), Vb[(size_t)((unsigned)e7)*64 + ln], av);
    }
    att_ws[(size_t)(b*2048 + q0 + q)*256 + h*64 + ln] = av / Z;
  }
}

// ---------- K3: distill(16x16 per group) + gate mix ----------
__global__ void mix_kernel(const float* __restrict__ att,
                           const float* __restrict__ Wd, const float* __restrict__ bd,
                           const float* __restrict__ gate, float* __restrict__ mix){
  __shared__ float wd_s[256];
  __shared__ float bd_s[16];
  const int tid = threadIdx.x;
  wd_s[tid] = Wd[tid];
  if (tid < 16) bd_s[tid] = bd[tid];
  __syncthreads();
  const int m = blockIdx.x*16 + (tid >> 4);
  const int j = tid & 15;
  const int b = m >> 11;
  const float* arow = att + (size_t)m*256;
  float* mrow = mix + (size_t)m*256;
  for (int g=0; g<16; g++){
    float d = bd_s[j];
    #pragma unroll
    for (int mm=0; mm<16; mm++) d = fmaf(arow[g*16+mm], wd_s[j*16+mm], d);
    const int cidx = g*16 + j;
    const float gt = gate[b*256 + cidx];
    mrow[cidx] = gt*d + (1.0f - gt)*arow[cidx];
  }
}

// ---------- K4: out = mixed @ Wo^T + bo ----------
__global__ __launch_bounds__(256) void out_gemm(
    const float* __restrict__ A, const float* __restrict__ Wo,
    const float* __restrict__ bo, float* __restrict__ out){
  __shared__ float As[16][68];
  __shared__ float Bs[16][68];
  const int m0 = blockIdx.x * 64;
  const int n0 = blockIdx.y * 64;
  const int tid = threadIdx.x;
  const int ty = tid >> 4, tx = tid & 15;
  const int lr = tid >> 2, lc = tid & 3;

  float c[4][4];
  #pragma unroll
  for (int i=0;i<4;i++){
    #pragma unroll
    for (int j=0;j<4;j++) c[i][j]=0.f;
  }

  for (int k0=0; k0<256; k0+=16){
    float4 av  = *(const float4*)&A[(size_t)(m0+lr)*256 + k0 + lc*4];
    float4 bv4 = *(const float4*)&Wo[(size_t)(n0+lr)*256 + k0 + lc*4];
    __syncthreads();
    As[lc*4+0][lr]=av.x;  As[lc*4+1][lr]=av.y;  As[lc*4+2][lr]=av.z;  As[lc*4+3][lr]=av.w;
    Bs[lc*4+0][lr]=bv4.x; Bs[lc*4+1][lr]=bv4.y; Bs[lc*4+2][lr]=bv4.z; Bs[lc*4+3][lr]=bv4.w;
    __syncthreads();
    #pragma unroll
    for (int kk=0; kk<16; kk++){
      float4 a  = *(const float4*)&As[kk][ty*4];
      float4 b4 = *(const float4*)&Bs[kk][tx*4];
      c[0][0]=fmaf(a.x,b4.x,c[0][0]); c[0][1]=fmaf(a.x,b4.y,c[0][1]); c[0][2]=fmaf(a.x,b4.z,c[0][2]); c[0][3]=fmaf(a.x,b4.w,c[0][3]);
      c[1][0]=fmaf(a.y,b4.x,c[1][0]); c[1][1]=fmaf(a.y,b4.y,c[1][1]); c[1][2]=fmaf(a.y,b4.z,c[1][2]); c[1][3]=fmaf(a.y,b4.w,c[1][3]);
      c[2][0]=fmaf(a.z,b4.x,c[2][0]); c[2][1]=fmaf(a.z,b4.y,c[2][1]); c[2][2]=fmaf(a.z,b4.z,c[2][2]); c[2][3]=fmaf(a.z,b4.w,c[2][3]);
      c[3][0]=fmaf(a.w,b4.x,c[3][0]); c[3][1]=fmaf(a.w,b4.y,c[3][1]); c[3][2]=fmaf(a.w,b4.z,c[3][2]); c[3][3]=fmaf(a.w,b4.w,c[3][3]);
    }
  }
  #pragma unroll
  for (int i=0;i<4;i++){
    const int m = m0 + ty*4 + i;
    float4 st = make_float4(c[i][0]+bo[n0+tx*4+0], c[i][1]+bo[n0+tx*4+1],
                            c[i][2]+bo[n0+tx*4+2], c[i][3]+bo[n0+tx*4+3]);
    *(float4*)&out[(size_t)m*256 + n0 + tx*4] = st;
  }
}

// ---------- launch ----------
extern "C" void kernel_launch(void* const* d_in, const int* in_sizes, int n_in,
                              void* d_out, int out_size, void* d_ws, size_t ws_size,
                              hipStream_t stream) {
  const float* x   = (const float*)d_in[0];
  const float* Wq  = (const float*)d_in[1];  const float* bq  = (const float*)d_in[2];
  const float* Wk  = (const float*)d_in[3];  const float* bk  = (const float*)d_in[4];
  const float* Wv  = (const float*)d_in[5];  const float* bv  = (const float*)d_in[6];
  const float* Wd  = (const float*)d_in[7];  const float* bd  = (const float*)d_in[8];
  const float* Wg  = (const float*)d_in[9];  const float* bg  = (const float*)d_in[10];
  const float* Wgp = (const float*)d_in[11]; const float* bgp = (const float*)d_in[12];
  const float* Wo  = (const float*)d_in[13]; const float* bo  = (const float*)d_in[14];

  float* ws = (float*)d_ws;
  float* q_ws   = ws;                 // 2,097,152
  float* kt_ws  = ws + 2097152;       // 2,097,152
  float* v_ws   = ws + 4194304;       // 2,097,152
  float* att_ws = ws + 6291456;       // 2,097,152
  float* mix_ws = ws + 8388608;       // 2,097,152
  float* xpart  = ws + 10485760;      // 16,384
  float* gate_ws= xpart + 16384;      // 1,024   (total ~42 MB)

  xpart_kernel<<<dim3(16,4), 256, 0, stream>>>(x, xpart);
  gate_kernel<<<1, 256, 0, stream>>>(xpart, Wg, bg, Wgp, bgp, gate_ws);
  qkv_gemm<<<dim3(128,12), 256, 0, stream>>>(x, Wq,bq, Wk,bk, Wv,bv, q_ws, kt_ws, v_ws);
  attn_kernel<<<dim3(128,16), 512, 0, stream>>>(q_ws, kt_ws, v_ws, att_ws);
  mix_kernel<<<512, 256, 0, stream>>>(att_ws, Wd, bd, gate_ws, mix_ws);
  out_gemm<<<dim3(128,4), 256, 0, stream>>>(mix_ws, Wo, bo, (float*)d_out);
}

// Round 2
// 479.876 us; speedup vs baseline: 1.4166x; 1.4166x over previous
//
#include <hip/hip_runtime.h>
#include <hip/hip_bf16.h>
#include <math.h>

// B=4, S=2048, D=256, H=4, HD=64; keep top-10% per score row.
// thr = v205 + 0.3*(v204 - v205)  (v_k = (k+1)-th largest)

#define CAP 256

typedef __attribute__((ext_vector_type(8))) short short8;
typedef __attribute__((ext_vector_type(4))) float floatx4;
#define MFMA16(a,b,c) __builtin_amdgcn_mfma_f32_16x16x32_bf16(a,b,c,0,0,0)

// ---------- helpers ----------
__device__ __forceinline__ unsigned mtu(float f){
  unsigned u = __float_as_uint(f);
  return (u & 0x80000000u) ? ~u : (u | 0x80000000u);
}
__device__ __forceinline__ float umt(unsigned u){
  return __uint_as_float((u & 0x80000000u) ? (u & 0x7fffffffu) : ~u);
}
__device__ __forceinline__ int wsum_i(int v){
  #pragma unroll
  for (int m=1;m<64;m<<=1) v += __shfl_xor(v,m,64);
  return v;
}
__device__ __forceinline__ float wsum_f(float v){
  #pragma unroll
  for (int m=1;m<64;m<<=1) v += __shfl_xor(v,m,64);
  return v;
}
__device__ __forceinline__ unsigned wmax_u(unsigned v){
  #pragma unroll
  for (int m=1;m<64;m<<=1){ unsigned o=(unsigned)__shfl_xor((int)v,m,64); v = o>v?o:v; }
  return v;
}
__device__ __forceinline__ unsigned wmin_u(unsigned v){
  #pragma unroll
  for (int m=1;m<64;m<<=1){ unsigned o=(unsigned)__shfl_xor((int)v,m,64); v = o<v?o:v; }
  return v;
}
__device__ __forceinline__ short8 ldb8(const __hip_bfloat16* p){
  return *(const short8*)p;
}

// ---------- K0a: per-(b,chunk) column sums of x ----------
__global__ void xpart_kernel(const float* __restrict__ x, float* __restrict__ xpart){
  const int ch = blockIdx.x, b = blockIdx.y, t = threadIdx.x;
  const float* xp = x + ((size_t)b*2048 + (size_t)ch*128)*256 + t;
  float s = 0.f;
  for (int i=0;i<128;i++) s += xp[(size_t)i*256];
  xpart[(size_t)(b*16+ch)*256 + t] = s;
}

// ---------- K0b: gate[b][256] ----------
__global__ void gate_kernel(const float* __restrict__ xpart,
                            const float* __restrict__ Wg, const float* __restrict__ bg,
                            const float* __restrict__ Wgp,const float* __restrict__ bgp,
                            float* __restrict__ gate_ws){
  __shared__ float xm[256];
  __shared__ float g16[16];
  const int t = threadIdx.x;
  for (int b=0;b<4;b++){
    float s = 0.f;
    for (int ch=0; ch<16; ch++) s += xpart[(size_t)(b*16+ch)*256 + t];
    xm[t] = s * (1.0f/2048.0f);
    __syncthreads();
    if (t < 16){
      float z = bg[t];
      for (int d=0; d<256; d++) z = fmaf(xm[d], Wg[t*256+d], z);
      g16[t] = 1.0f/(1.0f + __expf(-z));
    }
    __syncthreads();
    float z2 = bgp[t];
    #pragma unroll
    for (int j=0;j<16;j++) z2 = fmaf(g16[j], Wgp[t*16+j], z2);
    gate_ws[b*256 + t] = z2;
    __syncthreads();
  }
}

// ---------- K1: fused QKV projection (fp32 GEMM; Q/K emitted as bf16 hi/lo) ----------
__global__ __launch_bounds__(256) void qkv_gemm(
    const float* __restrict__ x,
    const float* __restrict__ Wq, const float* __restrict__ bq,
    const float* __restrict__ Wk, const float* __restrict__ bk,
    const float* __restrict__ Wv, const float* __restrict__ bv,
    __hip_bfloat16* __restrict__ qh, __hip_bfloat16* __restrict__ ql,
    __hip_bfloat16* __restrict__ kh, __hip_bfloat16* __restrict__ kl,
    float* __restrict__ v_ws){
  __shared__ float As[16][68];
  __shared__ float Bs[16][68];
  const int m0 = blockIdx.x * 64;
  const int n0g = blockIdx.y * 64;          // global col tile in [0,768)
  const int sect = n0g >> 8;                // 0:Q 1:K 2:V
  const int nloc0 = n0g & 255;
  const float* W    = (sect==0) ? Wq : ((sect==1) ? Wk : Wv);
  const float* bias = (sect==0) ? bq : ((sect==1) ? bk : bv);
  const int tid = threadIdx.x;
  const int ty = tid >> 4, tx = tid & 15;
  const int lr = tid >> 2, lc = tid & 3;

  float c[4][4];
  #pragma unroll
  for (int i=0;i<4;i++){
    #pragma unroll
    for (int j=0;j<4;j++) c[i][j]=0.f;
  }

  for (int k0=0; k0<256; k0+=16){
    float4 av  = *(const float4*)&x[(size_t)(m0+lr)*256 + k0 + lc*4];
    float4 bv4 = *(const float4*)&W[(size_t)(nloc0+lr)*256 + k0 + lc*4];
    __syncthreads();
    As[lc*4+0][lr]=av.x;  As[lc*4+1][lr]=av.y;  As[lc*4+2][lr]=av.z;  As[lc*4+3][lr]=av.w;
    Bs[lc*4+0][lr]=bv4.x; Bs[lc*4+1][lr]=bv4.y; Bs[lc*4+2][lr]=bv4.z; Bs[lc*4+3][lr]=bv4.w;
    __syncthreads();
    #pragma unroll
    for (int kk=0; kk<16; kk++){
      float4 a  = *(const float4*)&As[kk][ty*4];
      float4 b4 = *(const float4*)&Bs[kk][tx*4];
      c[0][0]=fmaf(a.x,b4.x,c[0][0]); c[0][1]=fmaf(a.x,b4.y,c[0][1]); c[0][2]=fmaf(a.x,b4.z,c[0][2]); c[0][3]=fmaf(a.x,b4.w,c[0][3]);
      c[1][0]=fmaf(a.y,b4.x,c[1][0]); c[1][1]=fmaf(a.y,b4.y,c[1][1]); c[1][2]=fmaf(a.y,b4.z,c[1][2]); c[1][3]=fmaf(a.y,b4.w,c[1][3]);
      c[2][0]=fmaf(a.z,b4.x,c[2][0]); c[2][1]=fmaf(a.z,b4.y,c[2][1]); c[2][2]=fmaf(a.z,b4.z,c[2][2]); c[2][3]=fmaf(a.z,b4.w,c[2][3]);
      c[3][0]=fmaf(a.w,b4.x,c[3][0]); c[3][1]=fmaf(a.w,b4.y,c[3][1]); c[3][2]=fmaf(a.w,b4.z,c[3][2]); c[3][3]=fmaf(a.w,b4.w,c[3][3]);
    }
  }

  #pragma unroll
  for (int i=0;i<4;i++){
    const int m = m0 + ty*4 + i;
    const int bidx = m >> 11, s = m & 2047;
    #pragma unroll
    for (int j=0;j<4;j++){
      const int f = nloc0 + tx*4 + j;        // feature in [0,256)
      const float val = c[i][j] + bias[f];
      const int hh = f >> 6, hd = f & 63;
      const size_t idx = (size_t)((bidx*4+hh)*2048 + s)*64 + hd;
      if (sect == 2){
        v_ws[idx] = val;
      } else {
        const __hip_bfloat16 hi = __float2bfloat16(val);
        const float lo = val - __bfloat162float(hi);
        if (sect == 0){ qh[idx] = hi; ql[idx] = __float2bfloat16(lo); }
        else          { kh[idx] = hi; kl[idx] = __float2bfloat16(lo); }
      }
    }
  }
}

// ---------- K2: sparse attention; MFMA scores + two-level exact quantile ----------
__global__ __launch_bounds__(512, 4) void attn_kernel(
    const __hip_bfloat16* __restrict__ qh, const __hip_bfloat16* __restrict__ ql,
    const __hip_bfloat16* __restrict__ kh, const __hip_bfloat16* __restrict__ kl,
    const float* __restrict__ v_ws, float* __restrict__ att_ws){
  __shared__ float buf[16][512];              // 32 KB score handoff chunk
  __shared__ unsigned short ks[16][CAP];      // 8 KB  kept keys
  __shared__ float ps[16][CAP];               // 16 KB kept probs (reused as cand scratch)

  const int bh = blockIdx.y;
  const int q0 = blockIdx.x * 16;
  const int tid = threadIdx.x;
  const int w = tid >> 6, ln = tid & 63;
  const int lm = ln & 15;
  const int lk = (ln >> 4) * 8;
  const int qa = 2*w, qb = 2*w + 1;

  const __hip_bfloat16* Qh = qh + ((size_t)bh*2048 + q0)*64;
  const __hip_bfloat16* Ql = ql + ((size_t)bh*2048 + q0)*64;
  const __hip_bfloat16* Kh = kh + ((size_t)bh*2048 + w*256)*64;
  const __hip_bfloat16* Kl = kl + ((size_t)bh*2048 + w*256)*64;

  unsigned su0[32], su1[32];

  // ----- rounds: MFMA 4 tiles -> LDS handoff -> each wave grabs its 2 rows -----
  #pragma unroll
  for (int c = 0; c < 4; c++){
    short8 ah0 = ldb8(Qh + lm*64 + lk);
    short8 ah1 = ldb8(Qh + lm*64 + 32 + lk);
    short8 al0 = ldb8(Ql + lm*64 + lk);
    short8 al1 = ldb8(Ql + lm*64 + 32 + lk);
    floatx4 acc[4];
    #pragma unroll
    for (int tl = 0; tl < 4; tl++){
      const int krow = c*64 + tl*16 + lm;
      short8 bh0 = ldb8(Kh + krow*64 + lk);
      short8 bh1 = ldb8(Kh + krow*64 + 32 + lk);
      short8 bl0 = ldb8(Kl + krow*64 + lk);
      short8 bl1 = ldb8(Kl + krow*64 + 32 + lk);
      floatx4 a = {0.f,0.f,0.f,0.f};
      a = MFMA16(ah0, bh0, a);
      a = MFMA16(ah1, bh1, a);
      a = MFMA16(al0, bh0, a);
      a = MFMA16(al1, bh1, a);
      a = MFMA16(ah0, bl0, a);
      a = MFMA16(ah1, bl1, a);
      a = MFMA16(al0, bl0, a);
      a = MFMA16(al1, bl1, a);
      acc[tl] = a;
    }
    __syncthreads();                      // previous chunk fully read
    const int wr = (ln >> 4) * 4;         // C-layout: row=(lane>>4)*4+reg, col=lane&15
    #pragma unroll
    for (int tl = 0; tl < 4; tl++){
      const int col = w*64 + tl*16 + lm;
      buf[wr+0][col] = acc[tl].x * 0.125f;
      buf[wr+1][col] = acc[tl].y * 0.125f;
      buf[wr+2][col] = acc[tl].z * 0.125f;
      buf[wr+3][col] = acc[tl].w * 0.125f;
    }
    __syncthreads();                      // chunk visible
    float4 ra0 = *(const float4*)&buf[qa][4*ln];
    float4 ra1 = *(const float4*)&buf[qa][256 + 4*ln];
    float4 rb0 = *(const float4*)&buf[qb][4*ln];
    float4 rb1 = *(const float4*)&buf[qb][256 + 4*ln];
    const int o = c*8;
    su0[o+0]=mtu(ra0.x); su0[o+1]=mtu(ra0.y); su0[o+2]=mtu(ra0.z); su0[o+3]=mtu(ra0.w);
    su0[o+4]=mtu(ra1.x); su0[o+5]=mtu(ra1.y); su0[o+6]=mtu(ra1.z); su0[o+7]=mtu(ra1.w);
    su1[o+0]=mtu(rb0.x); su1[o+1]=mtu(rb0.y); su1[o+2]=mtu(rb0.z); su1[o+3]=mtu(rb0.w);
    su1[o+4]=mtu(rb1.x); su1[o+5]=mtu(rb1.y); su1[o+6]=mtu(rb1.z); su1[o+7]=mtu(rb1.w);
  }
  // su index i (chunk c=i>>3, m=i&7) -> key:
  //   key = (ln>>4)*256 + ((m&4)<<8) + c*64 + (ln&15)*4 + (m&3)

  // ----- level-1: bisect top 16 bits (both rows packed) -----
  unsigned p0 = 0, p1 = 0;
  #pragma unroll 1
  for (int bit = 31; bit >= 16; --bit){
    const unsigned c0 = p0 | (1u << bit);
    const unsigned c1 = p1 | (1u << bit);
    int n0 = 0, n1 = 0;
    #pragma unroll
    for (int i = 0; i < 32; i++){
      n0 += (su0[i] >= c0) ? 1 : 0;
      n1 += (su1[i] >= c1) ? 1 : 0;
    }
    int packed = n0 | (n1 << 16);
    packed = wsum_i(packed);
    if ((packed & 0xffff) >= 206) p0 = c0;
    if ((packed >> 16)    >= 206) p1 = c1;
  }

  // ----- per-row: exact v205/v204, softmax, compaction, sparse PV -----
  const int b = bh >> 2, h = bh & 3;
  const float* Vb = v_ws + (size_t)bh * 2048 * 64;
  const unsigned long long lmask = (1ull << ln) - 1ull;
  const int kb = ((ln >> 4) << 8) + ((ln & 15) << 2);

  #pragma unroll
  for (int rr = 0; rr < 2; rr++){
    const int q = w*2 + rr;
    const unsigned p = rr ? p1 : p0;
    unsigned* candb = (unsigned*)ps[q];
    const unsigned hiu = p + 0x10000u;

    // one scan: above-count, min-above, row max, compact prefix-bucket candidates
    int above = 0, nc = 0;
    unsigned mnab = 0xffffffffu, mx = 0;
    #pragma unroll
    for (int i = 0; i < 32; i++){
      const unsigned u = rr ? su1[i] : su0[i];
      mx = (u > mx) ? u : mx;
      const bool ab = (u >= hiu);
      above += ab ? 1 : 0;
      if (ab && u < mnab) mnab = u;
      const bool cd = (u >= p) && !ab;
      const unsigned long long bal = __ballot(cd);
      if (cd){
        const int pos = nc + (int)__popcll(bal & lmask);
        if (pos < CAP) candb[pos] = u;
      }
      nc += (int)__popcll(bal);
    }
    above = wsum_i(above);
    mnab = wmin_u(mnab);
    mx = wmax_u(mx);

    unsigned v205u, v204u;
    if (nc <= CAP){
      const int j = 206 - above;          // j-th largest inside bucket
      unsigned cv0 = (ln       < nc) ? candb[ln]       : 0u;
      unsigned cv1 = (ln + 64  < nc) ? candb[ln + 64]  : 0u;
      unsigned cv2 = (ln + 128 < nc) ? candb[ln + 128] : 0u;
      unsigned cv3 = (ln + 192 < nc) ? candb[ln + 192] : 0u;
      unsigned v = p;
      #pragma unroll 1
      for (int bit = 15; bit >= 0; --bit){
        const unsigned c = v | (1u << bit);
        int n = ((cv0>=c)?1:0) + ((cv1>=c)?1:0) + ((cv2>=c)?1:0) + ((cv3>=c)?1:0);
        n = wsum_i(n);
        if (n >= j) v = c;
      }
      v205u = v;
      int cgtc = ((cv0>v)?1:0) + ((cv1>v)?1:0) + ((cv2>v)?1:0) + ((cv3>v)?1:0);
      unsigned mnc = 0xffffffffu;
      if (cv0 > v && cv0 < mnc) mnc = cv0;
      if (cv1 > v && cv1 < mnc) mnc = cv1;
      if (cv2 > v && cv2 < mnc) mnc = cv2;
      if (cv3 > v && cv3 < mnc) mnc = cv3;
      cgtc = wsum_i(cgtc);
      mnc = wmin_u(mnc);
      const int cgt = above + cgtc;
      v204u = (cgt == 205) ? ((cgtc > 0) ? mnc : mnab) : v205u;
    } else {
      // rare fallback: finish bisection over full register set
      unsigned v = p;
      #pragma unroll 1
      for (int bit = 15; bit >= 0; --bit){
        const unsigned c = v | (1u << bit);
        int n = 0;
        #pragma unroll
        for (int i = 0; i < 32; i++) n += ((rr ? su1[i] : su0[i]) >= c) ? 1 : 0;
        n = wsum_i(n);
        if (n >= 206) v = c;
      }
      v205u = v;
      int cgt = 0; unsigned mn = 0xffffffffu;
      #pragma unroll
      for (int i = 0; i < 32; i++){
        const unsigned u = rr ? su1[i] : su0[i];
        const bool gt = (u > v);
        cgt += gt ? 1 : 0;
        if (gt && u < mn) mn = u;
      }
      cgt = wsum_i(cgt);
      mn = wmin_u(mn);
      v204u = (cgt == 205) ? mn : v205u;
    }

    const float aa = umt(v205u), bb = umt(v204u);
    const float thr = (float)((double)aa + 0.3*((double)bb - (double)aa));
    const float mxf = umt(mx);

    int n = 0; float zl = 0.f;
    #pragma unroll
    for (int i = 0; i < 32; i++){
      const float s = umt(rr ? su1[i] : su0[i]);
      const bool keep = (s >= thr);
      const unsigned long long bal = __ballot(keep);
      if (keep){
        const float pr = __expf(s - mxf);
        zl += pr;
        const int pos = n + (int)__popcll(bal & lmask);
        if (pos < CAP){
          const int m = i & 7;
          const int key = kb + ((m & 4) << 8) + ((i >> 3) << 6) + (m & 3);
          ks[q][pos] = (unsigned short)key;
          ps[q][pos] = pr;
        }
      }
      n += (int)__popcll(bal);
    }
    float Z = wsum_f(zl);
    if (n > CAP) n = CAP;
    const int npad = (n + 7) & ~7;
    if (ln < npad - n){ ks[q][n + ln] = 0; ps[q][n + ln] = 0.f; }

    float av = 0.f;
    for (int t = 0; t < npad; t += 8){
      const int k0 = ks[q][t+0], k1 = ks[q][t+1], k2 = ks[q][t+2], k3 = ks[q][t+3];
      const int k4 = ks[q][t+4], k5 = ks[q][t+5], k6 = ks[q][t+6], k7 = ks[q][t+7];
      const float pr0 = ps[q][t+0], pr1 = ps[q][t+1], pr2 = ps[q][t+2], pr3 = ps[q][t+3];
      const float pr4 = ps[q][t+4], pr5 = ps[q][t+5], pr6 = ps[q][t+6], pr7 = ps[q][t+7];
      av = fmaf(pr0, Vb[(size_t)k0*64 + ln], av);
      av = fmaf(pr1, Vb[(size_t)k1*64 + ln], av);
      av = fmaf(pr2, Vb[(size_t)k2*64 + ln], av);
      av = fmaf(pr3, Vb[(size_t)k3*64 + ln], av);
      av = fmaf(pr4, Vb[(size_t)k4*64 + ln], av);
      av = fmaf(pr5, Vb[(size_t)k5*64 + ln], av);
      av = fmaf(pr6, Vb[(size_t)k6*64 + ln], av);
      av = fmaf(pr7, Vb[(size_t)k7*64 + ln], av);
    }
    att_ws[(size_t)(b*2048 + q0 + q)*256 + h*64 + ln] = av / Z;
  }
}

// ---------- K3: distill(16x16 per group) + gate mix ----------
__global__ void mix_kernel(const float* __restrict__ att,
                           const float* __restrict__ Wd, const float* __restrict__ bd,
                           const float* __restrict__ gate, float* __restrict__ mix){
  __shared__ float wd_s[256];
  __shared__ float bd_s[16];
  const int tid = threadIdx.x;
  wd_s[tid] = Wd[tid];
  if (tid < 16) bd_s[tid] = bd[tid];
  __syncthreads();
  const int m = blockIdx.x*16 + (tid >> 4);
  const int j = tid & 15;
  const int b = m >> 11;
  const float* arow = att + (size_t)m*256;
  float* mrow = mix + (size_t)m*256;
  for (int g=0; g<16; g++){
    float d = bd_s[j];
    #pragma unroll
    for (int mm=0; mm<16; mm++) d = fmaf(arow[g*16+mm], wd_s[j*16+mm], d);
    const int cidx = g*16 + j;
    const float gt = gate[b*256 + cidx];
    mrow[cidx] = gt*d + (1.0f - gt)*arow[cidx];
  }
}

// ---------- K4: out = mixed @ Wo^T + bo ----------
__global__ __launch_bounds__(256) void out_gemm(
    const float* __restrict__ A, const float* __restrict__ Wo,
    const float* __restrict__ bo, float* __restrict__ out){
  __shared__ float As[16][68];
  __shared__ float Bs[16][68];
  const int m0 = blockIdx.x * 64;
  const int n0 = blockIdx.y * 64;
  const int tid = threadIdx.x;
  const int ty = tid >> 4, tx = tid & 15;
  const int lr = tid >> 2, lc = tid & 3;

  float c[4][4];
  #pragma unroll
  for (int i=0;i<4;i++){
    #pragma unroll
    for (int j=0;j<4;j++) c[i][j]=0.f;
  }

  for (int k0=0; k0<256; k0+=16){
    float4 av  = *(const float4*)&A[(size_t)(m0+lr)*256 + k0 + lc*4];
    float4 bv4 = *(const float4*)&Wo[(size_t)(n0+lr)*256 + k0 + lc*4];
    __syncthreads();
    As[lc*4+0][lr]=av.x;  As[lc*4+1][lr]=av.y;  As[lc*4+2][lr]=av.z;  As[lc*4+3][lr]=av.w;
    Bs[lc*4+0][lr]=bv4.x; Bs[lc*4+1][lr]=bv4.y; Bs[lc*4+2][lr]=bv4.z; Bs[lc*4+3][lr]=bv4.w;
    __syncthreads();
    #pragma unroll
    for (int kk=0; kk<16; kk++){
      float4 a  = *(const float4*)&As[kk][ty*4];
      float4 b4 = *(const float4*)&Bs[kk][tx*4];
      c[0][0]=fmaf(a.x,b4.x,c[0][0]); c[0][1]=fmaf(a.x,b4.y,c[0][1]); c[0][2]=fmaf(a.x,b4.z,c[0][2]); c[0][3]=fmaf(a.x,b4.w,c[0][3]);
      c[1][0]=fmaf(a.y,b4.x,c[1][0]); c[1][1]=fmaf(a.y,b4.y,c[1][1]); c[1][2]=fmaf(a.y,b4.z,c[1][2]); c[1][3]=fmaf(a.y,b4.w,c[1][3]);
      c[2][0]=fmaf(a.z,b4.x,c[2][0]); c[2][1]=fmaf(a.z,b4.y,c[2][1]); c[2][2]=fmaf(a.z,b4.z,c[2][2]); c[2][3]=fmaf(a.z,b4.w,c[2][3]);
      c[3][0]=fmaf(a.w,b4.x,c[3][0]); c[3][1]=fmaf(a.w,b4.y,c[3][1]); c[3][2]=fmaf(a.w,b4.z,c[3][2]); c[3][3]=fmaf(a.w,b4.w,c[3][3]);
    }
  }
  #pragma unroll
  for (int i=0;i<4;i++){
    const int m = m0 + ty*4 + i;
    float4 st = make_float4(c[i][0]+bo[n0+tx*4+0], c[i][1]+bo[n0+tx*4+1],
                            c[i][2]+bo[n0+tx*4+2], c[i][3]+bo[n0+tx*4+3]);
    *(float4*)&out[(size_t)m*256 + n0 + tx*4] = st;
  }
}

// ---------- launch ----------
extern "C" void kernel_launch(void* const* d_in, const int* in_sizes, int n_in,
                              void* d_out, int out_size, void* d_ws, size_t ws_size,
                              hipStream_t stream) {
  const float* x   = (const float*)d_in[0];
  const float* Wq  = (const float*)d_in[1];  const float* bq  = (const float*)d_in[2];
  const float* Wk  = (const float*)d_in[3];  const float* bk  = (const float*)d_in[4];
  const float* Wv  = (const float*)d_in[5];  const float* bv  = (const float*)d_in[6];
  const float* Wd  = (const float*)d_in[7];  const float* bd  = (const float*)d_in[8];
  const float* Wg  = (const float*)d_in[9];  const float* bg  = (const float*)d_in[10];
  const float* Wgp = (const float*)d_in[11]; const float* bgp = (const float*)d_in[12];
  const float* Wo  = (const float*)d_in[13]; const float* bo  = (const float*)d_in[14];

  char* base = (char*)d_ws;
  float* v_ws   = (float*)(base);                       // 8 MB
  float* att_ws = (float*)(base + (size_t)( 8<<20));    // 8 MB
  float* mix_ws = (float*)(base + (size_t)(16<<20));    // 8 MB
  __hip_bfloat16* qh = (__hip_bfloat16*)(base + (size_t)(24<<20));  // 4 MB
  __hip_bfloat16* ql = (__hip_bfloat16*)(base + (size_t)(28<<20));  // 4 MB
  __hip_bfloat16* kh = (__hip_bfloat16*)(base + (size_t)(32<<20));  // 4 MB
  __hip_bfloat16* kl = (__hip_bfloat16*)(base + (size_t)(36<<20));  // 4 MB
  float* xpart  = (float*)(base + (size_t)(40<<20));    // 64 KB
  float* gate_ws= (float*)(base + (size_t)(40<<20) + 65536);

  xpart_kernel<<<dim3(16,4), 256, 0, stream>>>(x, xpart);
  gate_kernel<<<1, 256, 0, stream>>>(xpart, Wg, bg, Wgp, bgp, gate_ws);
  qkv_gemm<<<dim3(128,12), 256, 0, stream>>>(x, Wq,bq, Wk,bk, Wv,bv, qh,ql,kh,kl, v_ws);
  attn_kernel<<<dim3(128,16), 512, 0, stream>>>(qh, ql, kh, kl, v_ws, att_ws);
  mix_kernel<<<512, 256, 0, stream>>>(att_ws, Wd, bd, gate_ws, mix_ws);
  out_gemm<<<dim3(128,4), 256, 0, stream>>>(mix_ws, Wo, bo, (float*)d_out);
}